// Round 2
// baseline (269.024 us; speedup 1.0000x reference)
//
#include <hip/hip_runtime.h>

// Butterworth order-4 lowpass = 2 cascaded biquads (Direct Form II), fp32.
// B*C = 256 signals, T = 96000. Chunked linear-recurrence decomposition:
//  K1: per (signal, chunk) zero-state pass -> final 4-state
//  K2: sequential-over-chunks state composition via A = M^CLEN (4x4)
//  K3: per (signal, chunk) re-run with true initial state -> y
#define NSIG   256
#define T_LEN  96000
#define NCHUNK 250
#define CLEN   384   // T_LEN / NCHUNK

struct Coefs {
  float b01, b11, b21, na11, na21;   // section 0: b/a0, -a1/a0, -a2/a0
  float b02, b12, b22, na12, na22;   // section 1
};

__device__ __forceinline__ Coefs load_coefs(const float* __restrict__ sos) {
  Coefs c;
  float i0 = 1.0f / sos[3];
  c.b01 = sos[0] * i0; c.b11 = sos[1] * i0; c.b21 = sos[2] * i0;
  c.na11 = -sos[4] * i0; c.na21 = -sos[5] * i0;
  float i1 = 1.0f / sos[9];
  c.b02 = sos[6] * i1; c.b12 = sos[7] * i1; c.b22 = sos[8] * i1;
  c.na12 = -sos[10] * i1; c.na22 = -sos[11] * i1;
  return c;
}

// One sample through both sections. State = (w11,w21,w12,w22).
__device__ __forceinline__ float step2(float xin, float& w11, float& w21,
                                       float& w12, float& w22, const Coefs& c) {
  float w0 = fmaf(c.na11, w11, fmaf(c.na21, w21, xin));
  float y1 = fmaf(c.b21, w21, fmaf(c.b11, w11, c.b01 * w0));
  w21 = w11; w11 = w0;
  float w0b = fmaf(c.na12, w12, fmaf(c.na22, w22, y1));
  float y2 = fmaf(c.b22, w22, fmaf(c.b12, w12, c.b02 * w0b));
  w22 = w12; w12 = w0b;
  return y2;
}

// K1: zero-state chunk pass; store final state only.
__global__ __launch_bounds__(256) void k_phase1(const float* __restrict__ x,
                                                const float* __restrict__ sos,
                                                float4* __restrict__ vzs) {
  int tid = blockIdx.x * 256 + threadIdx.x;
  int sig = tid & (NSIG - 1);
  int chk = tid >> 8;                    // == blockIdx.x
  Coefs cf = load_coefs(sos);
  const float4* xp = reinterpret_cast<const float4*>(
      x + (size_t)sig * T_LEN + (size_t)chk * CLEN);
  float w11 = 0.f, w21 = 0.f, w12 = 0.f, w22 = 0.f;
#pragma unroll 4
  for (int j = 0; j < CLEN / 4; ++j) {
    float4 xv = xp[j];
    (void)step2(xv.x, w11, w21, w12, w22, cf);
    (void)step2(xv.y, w11, w21, w12, w22, cf);
    (void)step2(xv.z, w11, w21, w12, w22, cf);
    (void)step2(xv.w, w11, w21, w12, w22, cf);
  }
  float4 st; st.x = w11; st.y = w21; st.z = w12; st.w = w22;
  vzs[(size_t)chk * NSIG + sig] = st;    // coalesced across the block
}

// K2: one block. Lanes 0..3 build A = M^CLEN by evolving basis vectors with
// x=0; then each thread (= one signal) composes initial states across chunks:
//   v_init[0] = 0;  v_init[c+1] = A * v_init[c] + v_zs[c]
__global__ __launch_bounds__(256) void k_scan(const float* __restrict__ sos,
                                              const float4* __restrict__ vzs,
                                              float4* __restrict__ vinit) {
  __shared__ float Ash[16];
  Coefs cf = load_coefs(sos);
  int t = threadIdx.x;
  if (t < 4) {
    float w11 = (t == 0) ? 1.f : 0.f;
    float w21 = (t == 1) ? 1.f : 0.f;
    float w12 = (t == 2) ? 1.f : 0.f;
    float w22 = (t == 3) ? 1.f : 0.f;
    for (int j = 0; j < CLEN; ++j)
      (void)step2(0.f, w11, w21, w12, w22, cf);
    Ash[0 * 4 + t] = w11; Ash[1 * 4 + t] = w21;   // column t of A
    Ash[2 * 4 + t] = w12; Ash[3 * 4 + t] = w22;
  }
  __syncthreads();
  float A[16];
#pragma unroll
  for (int i = 0; i < 16; ++i) A[i] = Ash[i];
  float4 v; v.x = 0.f; v.y = 0.f; v.z = 0.f; v.w = 0.f;
  for (int c = 0; c < NCHUNK; ++c) {
    vinit[(size_t)c * NSIG + t] = v;               // state entering chunk c
    float4 z = vzs[(size_t)c * NSIG + t];
    float4 nv;
    nv.x = fmaf(A[ 3], v.w, fmaf(A[ 2], v.z, fmaf(A[ 1], v.y, fmaf(A[ 0], v.x, z.x))));
    nv.y = fmaf(A[ 7], v.w, fmaf(A[ 6], v.z, fmaf(A[ 5], v.y, fmaf(A[ 4], v.x, z.y))));
    nv.z = fmaf(A[11], v.w, fmaf(A[10], v.z, fmaf(A[ 9], v.y, fmaf(A[ 8], v.x, z.z))));
    nv.w = fmaf(A[15], v.w, fmaf(A[14], v.z, fmaf(A[13], v.y, fmaf(A[12], v.x, z.w))));
    v = nv;
  }
}

// K3: re-run each chunk with the true initial state, write y.
__global__ __launch_bounds__(256) void k_phase3(const float* __restrict__ x,
                                                const float* __restrict__ sos,
                                                const float4* __restrict__ vinit,
                                                float* __restrict__ y) {
  int tid = blockIdx.x * 256 + threadIdx.x;
  int sig = tid & (NSIG - 1);
  int chk = tid >> 8;
  Coefs cf = load_coefs(sos);
  size_t base = (size_t)sig * T_LEN + (size_t)chk * CLEN;
  const float4* xp = reinterpret_cast<const float4*>(x + base);
  float4* yp = reinterpret_cast<float4*>(y + base);
  float4 v = vinit[(size_t)chk * NSIG + sig];
  float w11 = v.x, w21 = v.y, w12 = v.z, w22 = v.w;
#pragma unroll 4
  for (int j = 0; j < CLEN / 4; ++j) {
    float4 xv = xp[j];
    float4 yv;
    yv.x = step2(xv.x, w11, w21, w12, w22, cf);
    yv.y = step2(xv.y, w11, w21, w12, w22, cf);
    yv.z = step2(xv.z, w11, w21, w12, w22, cf);
    yv.w = step2(xv.w, w11, w21, w12, w22, cf);
    yp[j] = yv;
  }
}

extern "C" void kernel_launch(void* const* d_in, const int* in_sizes, int n_in,
                              void* d_out, int out_size, void* d_ws, size_t ws_size,
                              hipStream_t stream) {
  const float* x   = (const float*)d_in[0];   // (32, 8, 96000) fp32
  const float* sos = (const float*)d_in[1];   // (2, 6) fp32
  float* yout = (float*)d_out;
  // ws layout: [vzs: NCHUNK*NSIG float4][vinit: NCHUNK*NSIG float4] = 2 MB
  float4* vzs   = (float4*)d_ws;
  float4* vinit = vzs + (size_t)NCHUNK * NSIG;

  k_phase1<<<NCHUNK, 256, 0, stream>>>(x, sos, vzs);
  k_scan<<<1, 256, 0, stream>>>(sos, vzs, vinit);
  k_phase3<<<NCHUNK, 256, 0, stream>>>(x, sos, vinit, yout);
}

// Round 5
// 241.096 us; speedup vs baseline: 1.1158x; 1.1158x over previous
//
#include <hip/hip_runtime.h>

// Butterworth order-4 lowpass = 2 cascaded biquads (Direct Form II), fp32.
// B*C = 256 signals, T = 96000. Chunked linear-recurrence decomposition:
//  K1: per (signal, chunk) zero-state pass -> final 4-state
//  K2: sequential-over-chunks state composition via A = M^CLEN (4x4)
//  K3: re-run each chunk with true initial state -> y
//
// R3 change: block = one signal, thread = chunk (wave spans contiguous 96 KB
// panel instead of 64 signals 384 KB apart) + 10-deep register prefetch in K2.
#define NSIG   256
#define T_LEN  96000
#define NCHUNK 250
#define CLEN   384   // T_LEN / NCHUNK

struct Coefs {
  float b01, b11, b21, na11, na21;   // section 0: b/a0, -a1/a0, -a2/a0
  float b02, b12, b22, na12, na22;   // section 1
};

__device__ __forceinline__ Coefs load_coefs(const float* __restrict__ sos) {
  Coefs c;
  float i0 = 1.0f / sos[3];
  c.b01 = sos[0] * i0; c.b11 = sos[1] * i0; c.b21 = sos[2] * i0;
  c.na11 = -sos[4] * i0; c.na21 = -sos[5] * i0;
  float i1 = 1.0f / sos[9];
  c.b02 = sos[6] * i1; c.b12 = sos[7] * i1; c.b22 = sos[8] * i1;
  c.na12 = -sos[10] * i1; c.na22 = -sos[11] * i1;
  return c;
}

// One sample through both sections. State = (w11,w21,w12,w22).
__device__ __forceinline__ float step2(float xin, float& w11, float& w21,
                                       float& w12, float& w22, const Coefs& c) {
  float w0 = fmaf(c.na11, w11, fmaf(c.na21, w21, xin));
  float y1 = fmaf(c.b21, w21, fmaf(c.b11, w11, c.b01 * w0));
  w21 = w11; w11 = w0;
  float w0b = fmaf(c.na12, w12, fmaf(c.na22, w22, y1));
  float y2 = fmaf(c.b22, w22, fmaf(c.b12, w12, c.b02 * w0b));
  w22 = w12; w12 = w0b;
  return y2;
}

// K1: zero-state chunk pass; store final state only.
// block = signal, thread = chunk: wave's 64 lanes span 64*1536 B contiguous.
__global__ __launch_bounds__(256) void k_phase1(const float* __restrict__ x,
                                                const float* __restrict__ sos,
                                                float4* __restrict__ vzs) {
  int sig = blockIdx.x;          // 0..255
  int chk = threadIdx.x;         // 0..255, active < 250
  if (chk >= NCHUNK) return;
  Coefs cf = load_coefs(sos);
  const float4* xp = reinterpret_cast<const float4*>(
      x + (size_t)sig * T_LEN + (size_t)chk * CLEN);
  float w11 = 0.f, w21 = 0.f, w12 = 0.f, w22 = 0.f;
#pragma unroll 8
  for (int j = 0; j < CLEN / 4; ++j) {
    float4 xv = xp[j];
    (void)step2(xv.x, w11, w21, w12, w22, cf);
    (void)step2(xv.y, w11, w21, w12, w22, cf);
    (void)step2(xv.z, w11, w21, w12, w22, cf);
    (void)step2(xv.w, w11, w21, w12, w22, cf);
  }
  float4 st; st.x = w11; st.y = w21; st.z = w12; st.w = w22;
  vzs[(size_t)chk * NSIG + sig] = st;   // scattered 16B x 250, tiny (1 MB total)
}

// K2: one block. Lanes 0..3 build A = M^CLEN by evolving basis vectors with
// x=0; then each thread (= one signal) composes initial states across chunks
// with a 10-deep register-prefetch pipeline (latency of L2/LLC loads hidden):
//   v_init[0] = 0;  v_init[c+1] = A * v_init[c] + v_zs[c]
#define PF 10   // NCHUNK = 25 groups * PF
__global__ __launch_bounds__(256) void k_scan(const float* __restrict__ sos,
                                              const float4* __restrict__ vzs,
                                              float4* __restrict__ vinit) {
  __shared__ float Ash[16];
  Coefs cf = load_coefs(sos);
  int t = threadIdx.x;
  if (t < 4) {
    float w11 = (t == 0) ? 1.f : 0.f;
    float w21 = (t == 1) ? 1.f : 0.f;
    float w12 = (t == 2) ? 1.f : 0.f;
    float w22 = (t == 3) ? 1.f : 0.f;
    for (int j = 0; j < CLEN; ++j)
      (void)step2(0.f, w11, w21, w12, w22, cf);
    Ash[0 * 4 + t] = w11; Ash[1 * 4 + t] = w21;   // column t of A
    Ash[2 * 4 + t] = w12; Ash[3 * 4 + t] = w22;
  }
  __syncthreads();
  float A[16];
#pragma unroll
  for (int i = 0; i < 16; ++i) A[i] = Ash[i];

  float4 zb[PF], zb2[PF];
#pragma unroll
  for (int i = 0; i < PF; ++i) zb[i] = vzs[(size_t)i * NSIG + t];
  float4 v; v.x = 0.f; v.y = 0.f; v.z = 0.f; v.w = 0.f;
  for (int g = 0; g < NCHUNK / PF; ++g) {
    // issue next group's loads before this group's FMA chain (indices clamped)
#pragma unroll
    for (int i = 0; i < PF; ++i) {
      int c2 = (g + 1) * PF + i;
      c2 = c2 < NCHUNK ? c2 : NCHUNK - 1;
      zb2[i] = vzs[(size_t)c2 * NSIG + t];
    }
#pragma unroll
    for (int i = 0; i < PF; ++i) {
      int c = g * PF + i;
      vinit[(size_t)c * NSIG + t] = v;             // state entering chunk c
      float4 z = zb[i];
      float4 nv;
      nv.x = fmaf(A[ 3], v.w, fmaf(A[ 2], v.z, fmaf(A[ 1], v.y, fmaf(A[ 0], v.x, z.x))));
      nv.y = fmaf(A[ 7], v.w, fmaf(A[ 6], v.z, fmaf(A[ 5], v.y, fmaf(A[ 4], v.x, z.y))));
      nv.z = fmaf(A[11], v.w, fmaf(A[10], v.z, fmaf(A[ 9], v.y, fmaf(A[ 8], v.x, z.z))));
      nv.w = fmaf(A[15], v.w, fmaf(A[14], v.z, fmaf(A[13], v.y, fmaf(A[12], v.x, z.w))));
      v = nv;
    }
#pragma unroll
    for (int i = 0; i < PF; ++i) zb[i] = zb2[i];
  }
}

// K3: re-run each chunk with the true initial state, write y.
__global__ __launch_bounds__(256) void k_phase3(const float* __restrict__ x,
                                                const float* __restrict__ sos,
                                                const float4* __restrict__ vinit,
                                                float* __restrict__ y) {
  int sig = blockIdx.x;
  int chk = threadIdx.x;
  if (chk >= NCHUNK) return;
  Coefs cf = load_coefs(sos);
  size_t base = (size_t)sig * T_LEN + (size_t)chk * CLEN;
  const float4* xp = reinterpret_cast<const float4*>(x + base);
  float4* yp = reinterpret_cast<float4*>(y + base);
  float4 v = vinit[(size_t)chk * NSIG + sig];
  float w11 = v.x, w21 = v.y, w12 = v.z, w22 = v.w;
#pragma unroll 8
  for (int j = 0; j < CLEN / 4; ++j) {
    float4 xv = xp[j];
    float4 yv;
    yv.x = step2(xv.x, w11, w21, w12, w22, cf);
    yv.y = step2(xv.y, w11, w21, w12, w22, cf);
    yv.z = step2(xv.z, w11, w21, w12, w22, cf);
    yv.w = step2(xv.w, w11, w21, w12, w22, cf);
    yp[j] = yv;
  }
}

extern "C" void kernel_launch(void* const* d_in, const int* in_sizes, int n_in,
                              void* d_out, int out_size, void* d_ws, size_t ws_size,
                              hipStream_t stream) {
  const float* x   = (const float*)d_in[0];   // (32, 8, 96000) fp32
  const float* sos = (const float*)d_in[1];   // (2, 6) fp32
  float* yout = (float*)d_out;
  // ws layout: [vzs: NCHUNK*NSIG float4][vinit: NCHUNK*NSIG float4] = 2 MB
  float4* vzs   = (float4*)d_ws;
  float4* vinit = vzs + (size_t)NCHUNK * NSIG;

  k_phase1<<<NSIG, 256, 0, stream>>>(x, sos, vzs);
  k_scan<<<1, 256, 0, stream>>>(sos, vzs, vinit);
  k_phase3<<<NSIG, 256, 0, stream>>>(x, sos, vinit, yout);
}